// Round 7
// baseline (1037.047 us; speedup 1.0000x reference)
//
#include <hip/hip_runtime.h>

typedef unsigned short u16;
typedef unsigned int   u32;

#define BATCH   2
#define SEQ     2048
#define DMODEL  4096
#define NHEADS  32
#define NKV     8
#define HDIM    128
#define QKV_DIM 6144

typedef __bf16 bf16x8 __attribute__((ext_vector_type(8)));
typedef float  f32x4  __attribute__((ext_vector_type(4)));

__device__ __forceinline__ float b2f(u16 u) {
  u32 x = ((u32)u) << 16;
  return __builtin_bit_cast(float, x);
}
__device__ __forceinline__ u16 f2b(float f) {
  u32 x = __builtin_bit_cast(u32, f);
  x = (x + 0x7FFFu + ((x >> 16) & 1u)) >> 16;  // RNE
  return (u16)x;
}
__device__ __forceinline__ float b2f_lo(u32 p) { return __builtin_bit_cast(float, p << 16); }
__device__ __forceinline__ float b2f_hi(u32 p) { return __builtin_bit_cast(float, p & 0xFFFF0000u); }

__device__ __forceinline__ u32 pk(float a, float b) {
  return (u32)f2b(a) | ((u32)f2b(b) << 16);
}

// async 16B global -> LDS (DMA; no VGPR round-trip). Dest must be linear in
// lane order within a wave (wave-uniform base + lane*16) -- our staging is.
__device__ __forceinline__ void gload16(const u16* __restrict__ g, u16* l) {
  __builtin_amdgcn_global_load_lds(
      (const __attribute__((address_space(1))) unsigned int*)(const void*)g,
      (__attribute__((address_space(3))) unsigned int*)(void*)l,
      16, 0, 0);
}

// ---------------------------------------------------------------------------
// fp32 -> bf16 bulk convert, 8 elems/thread, vectorized. (weights + x)
// ---------------------------------------------------------------------------
__global__ __launch_bounds__(256) void f32_to_bf16(const float* __restrict__ in,
                                                   u16* __restrict__ out, int n8) {
  const int i = blockIdx.x * 256 + threadIdx.x;
  if (i >= n8) return;
  const float4* p = (const float4*)(in + (size_t)i * 8);
  const float4 a = p[0], b = p[1];
  uint4 r;
  r.x = pk(a.x, a.y); r.y = pk(a.z, a.w); r.z = pk(b.x, b.y); r.w = pk(b.z, b.w);
  ((uint4*)out)[i] = r;
}

// ---------------------------------------------------------------------------
// GEMM, 256x256 tile, double-buffered single-barrier 2-phase (T3 minimum-2ph
// recipe, m230-V0 structure: 682 TF refcheck'd): C[m][n] = A[m][k]*W[n][k]+bias.
// 512 threads / 8 waves (2M x 4N), BK=64, per-wave output 128x64,
// acc = 8x4 f32x4 (128 VGPR). LDS = 2 x (32+32) KB = 128 KB -> 1 block/CU.
// Per K-step: STAGE(next buf) issued FIRST (8 x global_load_lds dwordx4 fly
// under compute), then 24 ds_read_b128 + 64 MFMA on cur buf, then one
// __syncthreads (compiler drains vmcnt(0) there -> next buf ready).
// No setprio (m190: negative on lockstep GEMM). XCD swizzle kept (nwg%8==0).
// MODE 0: scatter epilogue into bf16 Q/K/V; Q pre-scaled by 1/sqrt(d).
// MODE 1: fp32 C + bias.
// ---------------------------------------------------------------------------
template <int MODE>
__global__ __launch_bounds__(512) void gemm_bt3(const u16* __restrict__ Ab,
                                                const u16* __restrict__ Bw,
                                                const float* __restrict__ bias,
                                                float* __restrict__ outf,
                                                u16* __restrict__ oq,
                                                u16* __restrict__ ok,
                                                u16* __restrict__ ov,
                                                int K, int N) {
  __shared__ u16 As[2][256 * 64];   // 2 x 32 KB
  __shared__ u16 Bs[2][256 * 64];   // 2 x 32 KB
  const int t    = threadIdx.x;
  const int lane = t & 63;
  const int wv   = t >> 6;          // 0..7
  const int wr   = wv >> 2, wc = wv & 3;
  const int q4   = lane >> 4, l15 = lane & 15;

  // ---- XCD-aware block swizzle (bijective: nwg % 8 == 0) ----
  const int nwgx = gridDim.x;
  const int nwg  = nwgx * gridDim.y;
  int bid = blockIdx.y * nwgx + blockIdx.x;
  const int cpx = nwg >> 3;
  bid = (bid & 7) * cpx + (bid >> 3);
  const int m0 = (bid / nwgx) * 256, n0 = (bid % nwgx) * 256;

  f32x4 acc[8][4] = {};

  auto STAGE = [&](int buf, int k0) {
#pragma unroll
    for (int i = 0; i < 4; i++) {
      const int u = t + i * 512;               // 2048 units of 16B
      const int r = u >> 3, c8 = (u & 7) * 8;
      gload16(Bw + (size_t)(n0 + r) * K + k0 + c8, &Bs[buf][u * 8]);
    }
#pragma unroll
    for (int i = 0; i < 4; i++) {
      const int u = t + i * 512;
      const int r = u >> 3, c8 = (u & 7) * 8;
      gload16(Ab + (size_t)(m0 + r) * K + k0 + c8, &As[buf][u * 8]);
    }
  };

  auto COMPUTE = [&](int buf) {
#pragma unroll
    for (int kk = 0; kk < 2; kk++) {
      bf16x8 af[8], bfr[4];
#pragma unroll
      for (int i = 0; i < 8; i++)
        af[i] = *(const bf16x8*)&As[buf][(wr * 128 + i * 16 + l15) * 64 + kk * 32 + q4 * 8];
#pragma unroll
      for (int j = 0; j < 4; j++)
        bfr[j] = *(const bf16x8*)&Bs[buf][(wc * 64 + j * 16 + l15) * 64 + kk * 32 + q4 * 8];
#pragma unroll
      for (int i = 0; i < 8; i++)
#pragma unroll
        for (int j = 0; j < 4; j++)
          acc[i][j] = __builtin_amdgcn_mfma_f32_16x16x32_bf16(af[i], bfr[j], acc[i][j], 0, 0, 0);
    }
  };

  // prologue: fill buf0, drain, barrier
  STAGE(0, 0);
  __syncthreads();

  int cur = 0;
  for (int k0 = 64; k0 < K; k0 += 64) {
    STAGE(cur ^ 1, k0);     // next tile's DMA flies under this tile's MFMAs
    COMPUTE(cur);
    __syncthreads();        // drains vmcnt(0) -> next buf ready; readers done
    cur ^= 1;
  }
  COMPUTE(cur);             // epilogue tile (no prefetch)

  // ---- epilogue ----
#pragma unroll
  for (int j = 0; j < 4; j++) {
    const int gn = n0 + wc * 64 + j * 16 + l15;
    const float bv = bias[gn];
#pragma unroll
    for (int i = 0; i < 8; i++) {
      const int gmb = m0 + wr * 128 + i * 16 + q4 * 4;
#pragma unroll
      for (int rr = 0; rr < 4; rr++) {
        float val = acc[i][j][rr] + bv;
        const int gm = gmb + rr;
        if (MODE == 1) {
          outf[(size_t)gm * N + gn] = val;
        } else {
          const int b = gm >> 11, s = gm & (SEQ - 1);
          const int d = gn & (HDIM - 1);
          if (gn < 4096) {
            // fold attention scale 1/sqrt(128) into Q (commutes with RoPE)
            val *= 0.08838834764831845f;
            const int hh = gn >> 7;
            oq[((size_t)(b * NHEADS + hh) * SEQ + s) * HDIM + d] = f2b(val);
          } else if (gn < 5120) {
            const int hh = (gn - 4096) >> 7;
            ok[((size_t)(b * NKV + hh) * SEQ + s) * HDIM + d] = f2b(val);
          } else {
            const int hh = (gn - 5120) >> 7;
            ov[((size_t)(b * NKV + hh) * SEQ + s) * HDIM + d] = f2b(val);
          }
        }
      }
    }
  }
}

// ---------------------------------------------------------------------------
// RoPE in place on bf16 Q and K; cos/sin in fp32.
// ---------------------------------------------------------------------------
__global__ __launch_bounds__(256) void rope_kernel(u16* __restrict__ q, u16* __restrict__ kk,
                                                   int qrows, int totrows) {
  const int idx = blockIdx.x * 256 + threadIdx.x;
  const int row = idx >> 6;
  const int i   = idx & 63;
  if (row >= totrows) return;
  u16* base;
  int r;
  if (row < qrows) { base = q  + (size_t)row * HDIM;           r = row; }
  else             { base = kk + (size_t)(row - qrows) * HDIM; r = row - qrows; }
  const int s = r & (SEQ - 1);
  const float l2theta = 13.287712379549449f;  // log2(10000)
  const float inv = exp2f(-((float)(2 * i) * (1.0f / 128.0f)) * l2theta);
  const float ang = (float)s * inv;
  const float c  = cosf(ang);
  const float sn = sinf(ang);
  const u32 xv = *(const u32*)&base[2 * i];
  const float xr = b2f_lo(xv), xi = b2f_hi(xv);
  *(u32*)&base[2 * i] = pk(xr * c - xi * sn, xr * sn + xi * c);
}

// ---------------------------------------------------------------------------
// MFMA flash attention (causal, GQA group=4), SWAPPED-QK^T softmax.
// (unchanged from Round 6 -- launch_bounds(256,2), no scratch spill)
// ---------------------------------------------------------------------------
__global__ __launch_bounds__(256, 2) void attn_mfma(const u16* __restrict__ q,
                                                    const u16* __restrict__ k,
                                                    const u16* __restrict__ v,
                                                    u16* __restrict__ out) {
  __shared__ u16 Ks[64 * 136];       // [key][d], stride 136 u16 (272B)
  __shared__ u16 VtBuf[128 * 72];    // [d][key-swizzled], stride 72 u16 (144B)
  __shared__ u32 Ps32[4 * 32 * 36];  // per wave: [row][key-pair], stride 36 u32
  u32* Vt32 = (u32*)VtBuf;           // row stride 36 u32

  const int t    = threadIdx.x;
  const int lane = t & 63;
  const int w    = t >> 6;
  const int q4   = lane >> 4, l15 = lane & 15;
  const int qb   = 15 - (int)blockIdx.x;   // heavy blocks first
  const int h = blockIdx.y, b = blockIdx.z;
  const int m0 = qb * 128;
  const int mw = m0 + w * 32;              // wave's first q-row
  const int kvh = h >> 2;
  const u16* Qp = q + (size_t)(b * NHEADS + h) * SEQ * HDIM;
  const u16* Kp = k + (size_t)(b * NKV + kvh) * SEQ * HDIM;
  const u16* Vp = v + (size_t)(b * NKV + kvh) * SEQ * HDIM;

  // Q fragments (held in registers; Q already scaled by 1/sqrt(d))
  bf16x8 qf[2][4];
#pragma unroll
  for (int rt = 0; rt < 2; rt++)
#pragma unroll
    for (int kk = 0; kk < 4; kk++)
      qf[rt][kk] = *(const bf16x8*)&Qp[(size_t)(mw + rt * 16 + l15) * HDIM + kk * 32 + q4 * 8];

  f32x4 oacc[2][8] = {};
  float mrow[2], lrow[2];
  mrow[0] = mrow[1] = -1e30f;
  lrow[0] = lrow[1] = 0.f;

  u32* Pw32 = &Ps32[w * 32 * 36];

  const int nch = qb * 2 + 2;
  for (int kc = 0; kc < nch; kc++) {
    // ---- stage K: row-major, vector 16B units, coalesced (overlaps prev PV) ----
#pragma unroll
    for (int i = 0; i < 4; i++) {
      const int u = t + i * 256;           // 1024 units of 16B
      const int r = u >> 4, c = (u & 15) * 8;
      *(uint4*)&Ks[r * 136 + c] = *(const uint4*)&Kp[(size_t)(kc * 64 + r) * HDIM + c];
    }
    // ---- issue V loads now; consumed after softmax (latency hides under it) ----
    uint2 e0[4], e1[4];
#pragma unroll
    for (int i = 0; i < 4; i++) {
      const int tau = t + i * 256;         // 1024 tasks
      const int k2 = tau >> 5, dq = tau & 31;
      e0[i] = *(const uint2*)&Vp[(size_t)(kc * 64 + 2 * k2) * HDIM + dq * 4];
      e1[i] = *(const uint2*)&Vp[(size_t)(kc * 64 + 2 * k2 + 1) * HDIM + dq * 4];
    }
    __syncthreads();   // A: Ks published; prev-chunk Vt readers all done

    const bool part = (kc * 64 <= mw + 31);
    if (part) {
      const bool fullch = (kc * 64 + 63 <= mw);  // wave-uniform: no masking needed
      // ---- S^T = K Q^T (swapped operands) ----
      f32x4 sacc[2][4] = {};
      __builtin_amdgcn_s_setprio(1);
#pragma unroll
      for (int ct = 0; ct < 4; ct++) {
#pragma unroll
        for (int kk = 0; kk < 4; kk++) {
          const bf16x8 kb = *(const bf16x8*)&Ks[(ct * 16 + l15) * 136 + kk * 32 + q4 * 8];
          sacc[0][ct] = __builtin_amdgcn_mfma_f32_16x16x32_bf16(kb, qf[0][kk], sacc[0][ct], 0, 0, 0);
          sacc[1][ct] = __builtin_amdgcn_mfma_f32_16x16x32_bf16(kb, qf[1][kk], sacc[1][ct], 0, 0, 0);
        }
      }
      __builtin_amdgcn_s_setprio(0);
      // ---- softmax: lane owns 16 keys of q-row (rt*16+l15) ----
#pragma unroll
      for (int rt = 0; rt < 2; rt++) {
        float p[4][4];
        float cm[4];
        const int mm = mw + rt * 16 + l15;
#pragma unroll
        for (int ct = 0; ct < 4; ct++) {
#pragma unroll
          for (int rr = 0; rr < 4; rr++) {
            float s = sacc[rt][ct][rr];
            if (!fullch) {
              const int key = kc * 64 + ct * 16 + q4 * 4 + rr;
              s = (key <= mm) ? s : -1e30f;
            }
            p[ct][rr] = s;
          }
          cm[ct] = fmaxf(fmaxf(p[ct][0], p[ct][1]), fmaxf(p[ct][2], p[ct][3]));
        }
        float vmax = fmaxf(fmaxf(cm[0], cm[1]), fmaxf(cm[2], cm[3]));
        vmax = fmaxf(vmax, __shfl_xor(vmax, 16));
        vmax = fmaxf(vmax, __shfl_xor(vmax, 32));
        const float nm = fmaxf(mrow[rt], vmax);
        const float alpha = __expf(mrow[rt] - nm);
        mrow[rt] = nm;
        float cs[4];
#pragma unroll
        for (int ct = 0; ct < 4; ct++) {
#pragma unroll
          for (int rr = 0; rr < 4; rr++) p[ct][rr] = __expf(p[ct][rr] - nm);
          cs[ct] = (p[ct][0] + p[ct][1]) + (p[ct][2] + p[ct][3]);
        }
        lrow[rt] = lrow[rt] * alpha + ((cs[0] + cs[1]) + (cs[2] + cs[3]));
        // P -> LDS, packed u32 key-pairs (8B per ct); row spans u32 0..31
#pragma unroll
        for (int ct = 0; ct < 4; ct++) {
          uint2 w2;
          w2.x = pk(p[ct][0], p[ct][1]);
          w2.y = pk(p[ct][2], p[ct][3]);
          *(uint2*)&Pw32[(rt * 16 + l15) * 36 + ct * 8 + q4 * 2] = w2;
        }
        // alpha -> PV layout (row q4*4+rr) and rescale O
        float alT[4];
#pragma unroll
        for (int rr = 0; rr < 4; rr++) alT[rr] = __shfl(alpha, q4 * 4 + rr, 64);
#pragma unroll
        for (int dt = 0; dt < 8; dt++)
#pragma unroll
          for (int rr = 0; rr < 4; rr++) oacc[rt][dt][rr] *= alT[rr];
      }
    }
    // ---- commit V transposed: u32 key-pair packing + XOR group swizzle ----
#pragma unroll
    for (int i = 0; i < 4; i++) {
      const int tau = t + i * 256;
      const int k2 = tau >> 5, dq = tau & 31;
      u32 wj[4];
      wj[0] = (e0[i].x & 0xFFFFu) | (e1[i].x << 16);
      wj[1] = (e0[i].x >> 16)     | (e1[i].x & 0xFFFF0000u);
      wj[2] = (e0[i].y & 0xFFFFu) | (e1[i].y << 16);
      wj[3] = (e0[i].y >> 16)     | (e1[i].y & 0xFFFF0000u);
      const int g = k2 >> 2;
#pragma unroll
      for (int j = 0; j < 4; j++) {
        const int d = dq * 4 + j;
        const int gs = g ^ ((d >> 3) & 7);
        Vt32[d * 36 + gs * 4 + (k2 & 3)] = wj[j];
      }
    }
    __syncthreads();   // B: Vt published

    if (part) {
      // ---- O += P V ----
      __builtin_amdgcn_s_setprio(1);
#pragma unroll
      for (int kk2 = 0; kk2 < 2; kk2++) {
        bf16x8 pa[2];
        pa[0] = *(const bf16x8*)&Pw32[(l15) * 36 + kk2 * 16 + q4 * 4];
        pa[1] = *(const bf16x8*)&Pw32[(16 + l15) * 36 + kk2 * 16 + q4 * 4];
#pragma unroll
        for (int dt = 0; dt < 8; dt++) {
          const int d = dt * 16 + l15;
          const int gs = (kk2 * 4 + q4) ^ ((d >> 3) & 7);
          const bf16x8 vb = *(const bf16x8*)&Vt32[d * 36 + gs * 4];
          oacc[0][dt] = __builtin_amdgcn_mfma_f32_16x16x32_bf16(pa[0], vb, oacc[0][dt], 0, 0, 0);
          oacc[1][dt] = __builtin_amdgcn_mfma_f32_16x16x32_bf16(pa[1], vb, oacc[1][dt], 0, 0, 0);
        }
      }
      __builtin_amdgcn_s_setprio(0);
    }
  }

  // ---- epilogue: reduce l partials (4 q4-lanes), transpose to PV layout,
  //      O / l -> attn buffer [b][s][h*128+d] ----
#pragma unroll
  for (int rt = 0; rt < 2; rt++) {
    float ls = lrow[rt];
    ls += __shfl_xor(ls, 16);
    ls += __shfl_xor(ls, 32);
#pragma unroll
    for (int rr = 0; rr < 4; rr++) {
      const float lt = __shfl(ls, q4 * 4 + rr, 64);
      const float inv = 1.0f / lt;
      const int mm = mw + rt * 16 + q4 * 4 + rr;
      u16* op = &out[((size_t)(b * SEQ + mm)) * DMODEL + h * HDIM + l15];
#pragma unroll
      for (int dt = 0; dt < 8; dt++)
        op[dt * 16] = f2b(oacc[rt][dt][rr] * inv);
    }
  }
}

// ---------------------------------------------------------------------------
extern "C" void kernel_launch(void* const* d_in, const int* in_sizes, int n_in,
                              void* d_out, int out_size, void* d_ws, size_t ws_size,
                              hipStream_t stream) {
  const float* x     = (const float*)d_in[0];
  const float* w_qkv = (const float*)d_in[1];
  const float* b_qkv = (const float*)d_in[2];
  const float* w_o   = (const float*)d_in[3];
  const float* b_o   = (const float*)d_in[4];
  float* out = (float*)d_out;

  const size_t QN = (size_t)BATCH * NHEADS * SEQ * HDIM;   // 16.78M u16
  const size_t KN = (size_t)BATCH * NKV * SEQ * HDIM;      //  4.19M u16

  u16* q    = (u16*)d_ws;
  u16* k    = q + QN;
  u16* v    = k + KN;
  u16* attn = v + KN;
  u16* wb   = attn + QN;   // bf16 weight buffer: w_qkv (25.17M u16), reused for w_o
  u16* xb   = attn;        // bf16 x ALIASES attn: x is dead before attn_mfma writes

  const dim3 blk(256);
  const dim3 blk512(512);

  // ---- convert x and w_qkv -> bf16 ----
  const int n8_x = BATCH * SEQ * DMODEL / 8;
  f32_to_bf16<<<dim3(n8_x / 256), blk, 0, stream>>>(x, xb, n8_x);
  const int n8_qkv = QKV_DIM * DMODEL / 8;
  f32_to_bf16<<<dim3(n8_qkv / 256), blk, 0, stream>>>(w_qkv, wb, n8_qkv);

  // ---- QKV GEMM: 256^2 dbuf tiles; grid 24 x 16 = 384 blocks (%8==0) ----
  gemm_bt3<0><<<dim3(QKV_DIM / 256, (BATCH * SEQ) / 256), blk512, 0, stream>>>(
      xb, wb, b_qkv, nullptr, q, k, v, DMODEL, QKV_DIM);

  const int qrows = BATCH * NHEADS * SEQ;
  const int totrows = qrows + BATCH * NKV * SEQ;
  rope_kernel<<<dim3((totrows * 64) / 256), blk, 0, stream>>>(q, k, qrows, totrows);

  attn_mfma<<<dim3(SEQ / 128, NHEADS, BATCH), blk, 0, stream>>>(q, k, v, attn);

  // ---- convert w_o -> bf16 (reuses wb; w_qkv copy is dead now) ----
  const int n8_o = DMODEL * DMODEL / 8;
  f32_to_bf16<<<dim3(n8_o / 256), blk, 0, stream>>>(w_o, wb, n8_o);

  // ---- output GEMM: grid 16 x 16 = 256 blocks (%8==0) ----
  gemm_bt3<1><<<dim3(DMODEL / 256, (BATCH * SEQ) / 256), blk512, 0, stream>>>(
      attn, wb, b_o, out, nullptr, nullptr, nullptr, DMODEL, DMODEL);
}

// Round 9
// 914.454 us; speedup vs baseline: 1.1341x; 1.1341x over previous
//
#include <hip/hip_runtime.h>

typedef unsigned short u16;
typedef unsigned int   u32;

#define BATCH   2
#define SEQ     2048
#define DMODEL  4096
#define NHEADS  32
#define NKV     8
#define HDIM    128
#define QKV_DIM 6144

typedef __bf16 bf16x8 __attribute__((ext_vector_type(8)));
typedef float  f32x4  __attribute__((ext_vector_type(4)));

__device__ __forceinline__ float b2f(u16 u) {
  u32 x = ((u32)u) << 16;
  return __builtin_bit_cast(float, x);
}
__device__ __forceinline__ u16 f2b(float f) {
  u32 x = __builtin_bit_cast(u32, f);
  x = (x + 0x7FFFu + ((x >> 16) & 1u)) >> 16;  // RNE
  return (u16)x;
}
__device__ __forceinline__ float b2f_lo(u32 p) { return __builtin_bit_cast(float, p << 16); }
__device__ __forceinline__ float b2f_hi(u32 p) { return __builtin_bit_cast(float, p & 0xFFFF0000u); }

__device__ __forceinline__ u32 pk(float a, float b) {
  return (u32)f2b(a) | ((u32)f2b(b) << 16);
}

// async 16B global -> LDS (DMA; no VGPR round-trip). Dest must be linear in
// lane order within a wave (wave-uniform base + lane*16) -- our staging is.
__device__ __forceinline__ void gload16(const u16* __restrict__ g, u16* l) {
  __builtin_amdgcn_global_load_lds(
      (const __attribute__((address_space(1))) unsigned int*)(const void*)g,
      (__attribute__((address_space(3))) unsigned int*)(void*)l,
      16, 0, 0);
}

// Raw s_barrier pinned with sched_barrier(0) on BOTH sides.
// s_barrier is NOT a compiler memory fence: without the pins LLVM may hoist
// the next phase's ds_reads above it (reading LDS whose other-wave DMA hasn't
// landed -- vmcnt is per-wave; only the barrier extends it cross-wave), or
// sink stage-DMA issues below it (breaking ring WAR separation). R8's race.
__device__ __forceinline__ void barrier_pinned() {
  __builtin_amdgcn_sched_barrier(0);
  __builtin_amdgcn_s_barrier();
  __builtin_amdgcn_sched_barrier(0);
}

// ---------------------------------------------------------------------------
// fp32 -> bf16 bulk convert, 8 elems/thread, vectorized. (weights + x)
// ---------------------------------------------------------------------------
__global__ __launch_bounds__(256) void f32_to_bf16(const float* __restrict__ in,
                                                   u16* __restrict__ out, int n8) {
  const int i = blockIdx.x * 256 + threadIdx.x;
  if (i >= n8) return;
  const float4* p = (const float4*)(in + (size_t)i * 8);
  const float4 a = p[0], b = p[1];
  uint4 r;
  r.x = pk(a.x, a.y); r.y = pk(a.z, a.w); r.z = pk(b.x, b.y); r.w = pk(b.z, b.w);
  ((uint4*)out)[i] = r;
}

// stage one half-tile portion for this thread: 2 x gload16 into linear LDS.
// half-tile = [256 rows][32 k] u16 (16 KB); 1024 units; thread t does u=t,t+512.
__device__ __forceinline__ void stage_ht(const u16* __restrict__ gbase, int K,
                                         u16* __restrict__ dst, int t) {
#pragma unroll
  for (int j2 = 0; j2 < 2; j2++) {
    const int u = t + j2 * 512;
    const int r = u >> 2, cu = u & 3;       // 4 x 16B units per 64B row
    gload16(gbase + (size_t)r * K + cu * 8, &dst[u * 8]);
  }
}

// ---------------------------------------------------------------------------
// GEMM, 256x256 tile, 8-phase deep pipeline (T3+T4 counted-vmcnt + T5):
// C[m][n] = sum_k A[m][k]*W[n][k] + bias[n].  512 thr / 8 waves (2M x 4N),
// BK=64 split into 2 k-halves; half-tile = [256][32] u16 per operand.
// LDS: ring of 4 slots per operand (2dbuf x 2kh) = 128 KB.
// Per group g (=2*kt+kh), two phases:
//   ph A: 12 ds_read_b128 (8 A-frags + 4 B-frags) | stage A-ht(g+3) |
//         BARRIER | setprio1 | 16 MFMA (j=0,1) | setprio0 | BARRIER
//   ph B: stage B-ht(g+3) | setprio1 | 16 MFMA (j=2,3) | setprio0 |
//         [tile end: s_waitcnt vmcnt(4); vmcnt(0) before last tile] | BARRIER
// All barriers are sched_barrier-pinned raw s_barrier (no vmcnt drain);
// loads stay in flight across barriers (3 half-tile-groups ahead).
// [256][32] rows = 64B stride -> frag reads are 2-way bank-aliased = free.
// MODE 0: scatter epilogue into bf16 Q/K/V; Q pre-scaled by 1/sqrt(d).
// MODE 1: fp32 C + bias.
// ---------------------------------------------------------------------------
template <int MODE>
__global__ __launch_bounds__(512) void gemm_8ph(const u16* __restrict__ Ab,
                                                const u16* __restrict__ Bw,
                                                const float* __restrict__ bias,
                                                float* __restrict__ outf,
                                                u16* __restrict__ oq,
                                                u16* __restrict__ ok,
                                                u16* __restrict__ ov,
                                                int K, int N) {
  __shared__ u16 As[4][256 * 32];   // 4 x 16 KB
  __shared__ u16 Bs[4][256 * 32];   // 4 x 16 KB
  const int t    = threadIdx.x;
  const int lane = t & 63;
  const int wv   = t >> 6;          // 0..7
  const int wr   = wv >> 2, wc = wv & 3;
  const int q4   = lane >> 4, l15 = lane & 15;

  // ---- XCD-aware block swizzle (bijective: nwg % 8 == 0) ----
  const int nwgx = gridDim.x;
  const int nwg  = nwgx * gridDim.y;
  int bid = blockIdx.y * nwgx + blockIdx.x;
  const int cpx = nwg >> 3;
  bid = (bid & 7) * cpx + (bid >> 3);
  const int m0 = (bid / nwgx) * 256, n0 = (bid % nwgx) * 256;

  const u16* Abase = Ab + (size_t)m0 * K;
  const u16* Bbase = Bw + (size_t)n0 * K;
  const int NT = K >> 6;            // K-tiles of 64
  const int NHT = 2 * NT;           // k-half groups

  f32x4 acc[8][4] = {};

  // ---- prologue: stage ht 0,1,2 (A,B interleaved); keep newest ht in flight
#pragma unroll
  for (int m = 0; m < 3; m++) {
    const int koff = (m >> 1) * 64 + (m & 1) * 32;
    stage_ht(Abase + koff, K, &As[m & 3][0], t);
    stage_ht(Bbase + koff, K, &Bs[m & 3][0], t);
  }
  asm volatile("s_waitcnt vmcnt(4)" ::: "memory");   // ht0,ht1 landed (this wave)
  barrier_pinned();                                  // -> landed for ALL waves

  for (int kt = 0; kt < NT; kt++) {
#pragma unroll
    for (int kh = 0; kh < 2; kh++) {
      const int g  = 2 * kt + kh;
      const int sl = g & 3;
      const u16* Asl = &As[sl][0];
      const u16* Bsl = &Bs[sl][0];

      // ---- phase A: ds-reads + A-stage + barrier + MFMA(j=0,1) + barrier ----
      bf16x8 af[8], bfr[4];
#pragma unroll
      for (int i = 0; i < 8; i++)
        af[i] = *(const bf16x8*)&Asl[(wr * 128 + i * 16 + l15) * 32 + q4 * 8];
#pragma unroll
      for (int j = 0; j < 4; j++)
        bfr[j] = *(const bf16x8*)&Bsl[(wc * 64 + j * 16 + l15) * 32 + q4 * 8];

      const int ms = g + 3;                       // stage 3 half-tile-groups ahead
      const int koff = (ms >> 1) * 64 + (ms & 1) * 32;
      if (ms < NHT) stage_ht(Abase + koff, K, &As[ms & 3][0], t);

      barrier_pinned();
      __builtin_amdgcn_s_setprio(1);
#pragma unroll
      for (int i = 0; i < 8; i++) {
        acc[i][0] = __builtin_amdgcn_mfma_f32_16x16x32_bf16(af[i], bfr[0], acc[i][0], 0, 0, 0);
        acc[i][1] = __builtin_amdgcn_mfma_f32_16x16x32_bf16(af[i], bfr[1], acc[i][1], 0, 0, 0);
      }
      __builtin_amdgcn_s_setprio(0);
      barrier_pinned();

      // ---- phase B: B-stage + MFMA(j=2,3) + [boundary vmcnt] + barrier ----
      if (ms < NHT) stage_ht(Bbase + koff, K, &Bs[ms & 3][0], t);
      __builtin_amdgcn_s_setprio(1);
#pragma unroll
      for (int i = 0; i < 8; i++) {
        acc[i][2] = __builtin_amdgcn_mfma_f32_16x16x32_bf16(af[i], bfr[2], acc[i][2], 0, 0, 0);
        acc[i][3] = __builtin_amdgcn_mfma_f32_16x16x32_bf16(af[i], bfr[3], acc[i][3], 0, 0, 0);
      }
      __builtin_amdgcn_s_setprio(0);
      if (kh == 1) {
        if (kt < NT - 2)       asm volatile("s_waitcnt vmcnt(4)" ::: "memory");
        else if (kt == NT - 2) asm volatile("s_waitcnt vmcnt(0)" ::: "memory");
      }
      barrier_pinned();
    }
  }

  // ---- epilogue ----
#pragma unroll
  for (int j = 0; j < 4; j++) {
    const int gn = n0 + wc * 64 + j * 16 + l15;
    const float bv = bias[gn];
#pragma unroll
    for (int i = 0; i < 8; i++) {
      const int gmb = m0 + wr * 128 + i * 16 + q4 * 4;
#pragma unroll
      for (int rr = 0; rr < 4; rr++) {
        float val = acc[i][j][rr] + bv;
        const int gm = gmb + rr;
        if (MODE == 1) {
          outf[(size_t)gm * N + gn] = val;
        } else {
          const int b = gm >> 11, s = gm & (SEQ - 1);
          const int d = gn & (HDIM - 1);
          if (gn < 4096) {
            // fold attention scale 1/sqrt(128) into Q (commutes with RoPE)
            val *= 0.08838834764831845f;
            const int hh = gn >> 7;
            oq[((size_t)(b * NHEADS + hh) * SEQ + s) * HDIM + d] = f2b(val);
          } else if (gn < 5120) {
            const int hh = (gn - 4096) >> 7;
            ok[((size_t)(b * NKV + hh) * SEQ + s) * HDIM + d] = f2b(val);
          } else {
            const int hh = (gn - 5120) >> 7;
            ov[((size_t)(b * NKV + hh) * SEQ + s) * HDIM + d] = f2b(val);
          }
        }
      }
    }
  }
}

// ---------------------------------------------------------------------------
// RoPE in place on bf16 Q and K; cos/sin in fp32.
// ---------------------------------------------------------------------------
__global__ __launch_bounds__(256) void rope_kernel(u16* __restrict__ q, u16* __restrict__ kk,
                                                   int qrows, int totrows) {
  const int idx = blockIdx.x * 256 + threadIdx.x;
  const int row = idx >> 6;
  const int i   = idx & 63;
  if (row >= totrows) return;
  u16* base;
  int r;
  if (row < qrows) { base = q  + (size_t)row * HDIM;           r = row; }
  else             { base = kk + (size_t)(row - qrows) * HDIM; r = row - qrows; }
  const int s = r & (SEQ - 1);
  const float l2theta = 13.287712379549449f;  // log2(10000)
  const float inv = exp2f(-((float)(2 * i) * (1.0f / 128.0f)) * l2theta);
  const float ang = (float)s * inv;
  const float c  = cosf(ang);
  const float sn = sinf(ang);
  const u32 xv = *(const u32*)&base[2 * i];
  const float xr = b2f_lo(xv), xi = b2f_hi(xv);
  *(u32*)&base[2 * i] = pk(xr * c - xi * sn, xr * sn + xi * c);
}

// ---------------------------------------------------------------------------
// MFMA flash attention (causal, GQA group=4), SWAPPED-QK^T softmax.
// (unchanged from Round 6 -- launch_bounds(256,2), no scratch spill)
// ---------------------------------------------------------------------------
__global__ __launch_bounds__(256, 2) void attn_mfma(const u16* __restrict__ q,
                                                    const u16* __restrict__ k,
                                                    const u16* __restrict__ v,
                                                    u16* __restrict__ out) {
  __shared__ u16 Ks[64 * 136];       // [key][d], stride 136 u16 (272B)
  __shared__ u16 VtBuf[128 * 72];    // [d][key-swizzled], stride 72 u16 (144B)
  __shared__ u32 Ps32[4 * 32 * 36];  // per wave: [row][key-pair], stride 36 u32
  u32* Vt32 = (u32*)VtBuf;           // row stride 36 u32

  const int t    = threadIdx.x;
  const int lane = t & 63;
  const int w    = t >> 6;
  const int q4   = lane >> 4, l15 = lane & 15;
  const int qb   = 15 - (int)blockIdx.x;   // heavy blocks first
  const int h = blockIdx.y, b = blockIdx.z;
  const int m0 = qb * 128;
  const int mw = m0 + w * 32;              // wave's first q-row
  const int kvh = h >> 2;
  const u16* Qp = q + (size_t)(b * NHEADS + h) * SEQ * HDIM;
  const u16* Kp = k + (size_t)(b * NKV + kvh) * SEQ * HDIM;
  const u16* Vp = v + (size_t)(b * NKV + kvh) * SEQ * HDIM;

  // Q fragments (held in registers; Q already scaled by 1/sqrt(d))
  bf16x8 qf[2][4];
#pragma unroll
  for (int rt = 0; rt < 2; rt++)
#pragma unroll
    for (int kk = 0; kk < 4; kk++)
      qf[rt][kk] = *(const bf16x8*)&Qp[(size_t)(mw + rt * 16 + l15) * HDIM + kk * 32 + q4 * 8];

  f32x4 oacc[2][8] = {};
  float mrow[2], lrow[2];
  mrow[0] = mrow[1] = -1e30f;
  lrow[0] = lrow[1] = 0.f;

  u32* Pw32 = &Ps32[w * 32 * 36];

  const int nch = qb * 2 + 2;
  for (int kc = 0; kc < nch; kc++) {
    // ---- stage K: row-major, vector 16B units, coalesced (overlaps prev PV) ----
#pragma unroll
    for (int i = 0; i < 4; i++) {
      const int u = t + i * 256;           // 1024 units of 16B
      const int r = u >> 4, c = (u & 15) * 8;
      *(uint4*)&Ks[r * 136 + c] = *(const uint4*)&Kp[(size_t)(kc * 64 + r) * HDIM + c];
    }
    // ---- issue V loads now; consumed after softmax (latency hides under it) ----
    uint2 e0[4], e1[4];
#pragma unroll
    for (int i = 0; i < 4; i++) {
      const int tau = t + i * 256;         // 1024 tasks
      const int k2 = tau >> 5, dq = tau & 31;
      e0[i] = *(const uint2*)&Vp[(size_t)(kc * 64 + 2 * k2) * HDIM + dq * 4];
      e1[i] = *(const uint2*)&Vp[(size_t)(kc * 64 + 2 * k2 + 1) * HDIM + dq * 4];
    }
    __syncthreads();   // A: Ks published; prev-chunk Vt readers all done

    const bool part = (kc * 64 <= mw + 31);
    if (part) {
      const bool fullch = (kc * 64 + 63 <= mw);  // wave-uniform: no masking needed
      // ---- S^T = K Q^T (swapped operands) ----
      f32x4 sacc[2][4] = {};
      __builtin_amdgcn_s_setprio(1);
#pragma unroll
      for (int ct = 0; ct < 4; ct++) {
#pragma unroll
        for (int kk = 0; kk < 4; kk++) {
          const bf16x8 kb = *(const bf16x8*)&Ks[(ct * 16 + l15) * 136 + kk * 32 + q4 * 8];
          sacc[0][ct] = __builtin_amdgcn_mfma_f32_16x16x32_bf16(kb, qf[0][kk], sacc[0][ct], 0, 0, 0);
          sacc[1][ct] = __builtin_amdgcn_mfma_f32_16x16x32_bf16(kb, qf[1][kk], sacc[1][ct], 0, 0, 0);
        }
      }
      __builtin_amdgcn_s_setprio(0);
      // ---- softmax: lane owns 16 keys of q-row (rt*16+l15) ----
#pragma unroll
      for (int rt = 0; rt < 2; rt++) {
        float p[4][4];
        float cm[4];
        const int mm = mw + rt * 16 + l15;
#pragma unroll
        for (int ct = 0; ct < 4; ct++) {
#pragma unroll
          for (int rr = 0; rr < 4; rr++) {
            float s = sacc[rt][ct][rr];
            if (!fullch) {
              const int key = kc * 64 + ct * 16 + q4 * 4 + rr;
              s = (key <= mm) ? s : -1e30f;
            }
            p[ct][rr] = s;
          }
          cm[ct] = fmaxf(fmaxf(p[ct][0], p[ct][1]), fmaxf(p[ct][2], p[ct][3]));
        }
        float vmax = fmaxf(fmaxf(cm[0], cm[1]), fmaxf(cm[2], cm[3]));
        vmax = fmaxf(vmax, __shfl_xor(vmax, 16));
        vmax = fmaxf(vmax, __shfl_xor(vmax, 32));
        const float nm = fmaxf(mrow[rt], vmax);
        const float alpha = __expf(mrow[rt] - nm);
        mrow[rt] = nm;
        float cs[4];
#pragma unroll
        for (int ct = 0; ct < 4; ct++) {
#pragma unroll
          for (int rr = 0; rr < 4; rr++) p[ct][rr] = __expf(p[ct][rr] - nm);
          cs[ct] = (p[ct][0] + p[ct][1]) + (p[ct][2] + p[ct][3]);
        }
        lrow[rt] = lrow[rt] * alpha + ((cs[0] + cs[1]) + (cs[2] + cs[3]));
        // P -> LDS, packed u32 key-pairs (8B per ct); row spans u32 0..31
#pragma unroll
        for (int ct = 0; ct < 4; ct++) {
          uint2 w2;
          w2.x = pk(p[ct][0], p[ct][1]);
          w2.y = pk(p[ct][2], p[ct][3]);
          *(uint2*)&Pw32[(rt * 16 + l15) * 36 + ct * 8 + q4 * 2] = w2;
        }
        // alpha -> PV layout (row q4*4+rr) and rescale O
        float alT[4];
#pragma unroll
        for (int rr = 0; rr < 4; rr++) alT[rr] = __shfl(alpha, q4 * 4 + rr, 64);
#pragma unroll
        for (int dt = 0; dt < 8; dt++)
#pragma unroll
          for (int rr = 0; rr < 4; rr++) oacc[rt][dt][rr] *= alT[rr];
      }
    }
    // ---- commit V transposed: u32 key-pair packing + XOR group swizzle ----
#pragma unroll
    for (int i = 0; i < 4; i++) {
      const int tau = t + i * 256;
      const int k2 = tau >> 5, dq = tau & 31;
      u32 wj[4];
      wj[0] = (e0[i].x & 0xFFFFu) | (e1[i].x << 16);
      wj[1] = (e0[i].x >> 16)     | (e1[i].x & 0xFFFF0000u);
      wj[2] = (e0[i].y & 0xFFFFu) | (e1[i].y << 16);
      wj[3] = (e0[i].y >> 16)     | (e1[i].y & 0xFFFF0000u);
      const int g = k2 >> 2;
#pragma unroll
      for (int j = 0; j < 4; j++) {
        const int d = dq * 4 + j;
        const int gs = g ^ ((d >> 3) & 7);
        Vt32[d * 36 + gs * 4 + (k2 & 3)] = wj[j];
      }
    }
    __syncthreads();   // B: Vt published

    if (part) {
      // ---- O += P V ----
      __builtin_amdgcn_s_setprio(1);
#pragma unroll
      for (int kk2 = 0; kk2 < 2; kk2++) {
        bf16x8 pa[2];
        pa[0] = *(const bf16x8*)&Pw32[(l15) * 36 + kk2 * 16 + q4 * 4];
        pa[1] = *(const bf16x8*)&Pw32[(16 + l15) * 36 + kk2 * 16 + q4 * 4];
#pragma unroll
        for (int dt = 0; dt < 8; dt++) {
          const int d = dt * 16 + l15;
          const int gs = (kk2 * 4 + q4) ^ ((d >> 3) & 7);
          const bf16x8 vb = *(const bf16x8*)&Vt32[d * 36 + gs * 4];
          oacc[0][dt] = __builtin_amdgcn_mfma_f32_16x16x32_bf16(pa[0], vb, oacc[0][dt], 0, 0, 0);
          oacc[1][dt] = __builtin_amdgcn_mfma_f32_16x16x32_bf16(pa[1], vb, oacc[1][dt], 0, 0, 0);
        }
      }
      __builtin_amdgcn_s_setprio(0);
    }
  }

  // ---- epilogue: reduce l partials (4 q4-lanes), transpose to PV layout,
  //      O / l -> attn buffer [b][s][h*128+d] ----
#pragma unroll
  for (int rt = 0; rt < 2; rt++) {
    float ls = lrow[rt];
    ls += __shfl_xor(ls, 16);
    ls += __shfl_xor(ls, 32);
#pragma unroll
    for (int rr = 0; rr < 4; rr++) {
      const float lt = __shfl(ls, q4 * 4 + rr, 64);
      const float inv = 1.0f / lt;
      const int mm = mw + rt * 16 + q4 * 4 + rr;
      u16* op = &out[((size_t)(b * SEQ + mm)) * DMODEL + h * HDIM + l15];
#pragma unroll
      for (int dt = 0; dt < 8; dt++)
        op[dt * 16] = f2b(oacc[rt][dt][rr] * inv);
    }
  }
}

// ---------------------------------------------------------------------------
extern "C" void kernel_launch(void* const* d_in, const int* in_sizes, int n_in,
                              void* d_out, int out_size, void* d_ws, size_t ws_size,
                              hipStream_t stream) {
  const float* x     = (const float*)d_in[0];
  const float* w_qkv = (const float*)d_in[1];
  const float* b_qkv = (const float*)d_in[2];
  const float* w_o   = (const float*)d_in[3];
  const float* b_o   = (const float*)d_in[4];
  float* out = (float*)d_out;

  const size_t QN = (size_t)BATCH * NHEADS * SEQ * HDIM;   // 16.78M u16
  const size_t KN = (size_t)BATCH * NKV * SEQ * HDIM;      //  4.19M u16

  u16* q    = (u16*)d_ws;
  u16* k    = q + QN;
  u16* v    = k + KN;
  u16* attn = v + KN;
  u16* wb   = attn + QN;   // bf16 weight buffer: w_qkv (25.17M u16), reused for w_o
  u16* xb   = attn;        // bf16 x ALIASES attn: x is dead before attn_mfma writes

  const dim3 blk(256);
  const dim3 blk512(512);

  // ---- convert x and w_qkv -> bf16 ----
  const int n8_x = BATCH * SEQ * DMODEL / 8;
  f32_to_bf16<<<dim3(n8_x / 256), blk, 0, stream>>>(x, xb, n8_x);
  const int n8_qkv = QKV_DIM * DMODEL / 8;
  f32_to_bf16<<<dim3(n8_qkv / 256), blk, 0, stream>>>(w_qkv, wb, n8_qkv);

  // ---- QKV GEMM: 256^2 8-phase; grid 24 x 16 = 384 blocks (%8==0) ----
  gemm_8ph<0><<<dim3(QKV_DIM / 256, (BATCH * SEQ) / 256), blk512, 0, stream>>>(
      xb, wb, b_qkv, nullptr, q, k, v, DMODEL, QKV_DIM);

  const int qrows = BATCH * NHEADS * SEQ;
  const int totrows = qrows + BATCH * NKV * SEQ;
  rope_kernel<<<dim3((totrows * 64) / 256), blk, 0, stream>>>(q, k, qrows, totrows);

  attn_mfma<<<dim3(SEQ / 128, NHEADS, BATCH), blk, 0, stream>>>(q, k, v, attn);

  // ---- convert w_o -> bf16 (reuses wb; w_qkv copy is dead now) ----
  const int n8_o = DMODEL * DMODEL / 8;
  f32_to_bf16<<<dim3(n8_o / 256), blk, 0, stream>>>(w_o, wb, n8_o);

  // ---- output GEMM: grid 16 x 16 = 256 blocks (%8==0) ----
  gemm_8ph<1><<<dim3(DMODEL / 256, (BATCH * SEQ) / 256), blk512, 0, stream>>>(
      attn, wb, b_o, out, nullptr, nullptr, nullptr, DMODEL, DMODEL);
}

// Round 10
// 869.790 us; speedup vs baseline: 1.1923x; 1.0513x over previous
//
#include <hip/hip_runtime.h>

typedef unsigned short u16;
typedef unsigned int   u32;

#define BATCH   2
#define SEQ     2048
#define DMODEL  4096
#define NHEADS  32
#define NKV     8
#define HDIM    128
#define QKV_DIM 6144

typedef __bf16 bf16x8 __attribute__((ext_vector_type(8)));
typedef float  f32x4  __attribute__((ext_vector_type(4)));

__device__ __forceinline__ float b2f(u16 u) {
  u32 x = ((u32)u) << 16;
  return __builtin_bit_cast(float, x);
}
__device__ __forceinline__ u16 f2b(float f) {
  u32 x = __builtin_bit_cast(u32, f);
  x = (x + 0x7FFFu + ((x >> 16) & 1u)) >> 16;  // RNE
  return (u16)x;
}
__device__ __forceinline__ float b2f_lo(u32 p) { return __builtin_bit_cast(float, p << 16); }
__device__ __forceinline__ float b2f_hi(u32 p) { return __builtin_bit_cast(float, p & 0xFFFF0000u); }

__device__ __forceinline__ u32 pk(float a, float b) {
  return (u32)f2b(a) | ((u32)f2b(b) << 16);
}

// async 16B global -> LDS (DMA; no VGPR round-trip). Dest must be linear in
// lane order within a wave (wave-uniform base + lane*16) -- our staging is.
__device__ __forceinline__ void gload16(const u16* __restrict__ g, u16* l) {
  __builtin_amdgcn_global_load_lds(
      (const __attribute__((address_space(1))) unsigned int*)(const void*)g,
      (__attribute__((address_space(3))) unsigned int*)(void*)l,
      16, 0, 0);
}

// Raw s_barrier pinned with sched_barrier(0) on BOTH sides.
// s_barrier is NOT a compiler memory fence: without the pins LLVM may hoist
// the next phase's ds_reads above it (reading LDS whose other-wave DMA hasn't
// landed -- vmcnt is per-wave; only the barrier extends it cross-wave), or
// sink stage-DMA issues below it (breaking ring WAR separation). R8's race.
__device__ __forceinline__ void barrier_pinned() {
  __builtin_amdgcn_sched_barrier(0);
  __builtin_amdgcn_s_barrier();
  __builtin_amdgcn_sched_barrier(0);
}

// ---------------------------------------------------------------------------
// fp32 -> bf16 bulk convert, 8 elems/thread, vectorized. (weights + x)
// ---------------------------------------------------------------------------
__global__ __launch_bounds__(256) void f32_to_bf16(const float* __restrict__ in,
                                                   u16* __restrict__ out, int n8) {
  const int i = blockIdx.x * 256 + threadIdx.x;
  if (i >= n8) return;
  const float4* p = (const float4*)(in + (size_t)i * 8);
  const float4 a = p[0], b = p[1];
  uint4 r;
  r.x = pk(a.x, a.y); r.y = pk(a.z, a.w); r.z = pk(b.x, b.y); r.w = pk(b.z, b.w);
  ((uint4*)out)[i] = r;
}

// stage one half-tile portion: 2 x gload16 into LINEAR LDS with the global
// SOURCE pre-swizzled (rule #21: swizzle both sides or neither; gload_lds
// dest must stay linear).  LDS unit (r,cu) holds global unit cu^((r>>1)&3).
// T2 fix for the 64B-row 8-way bank conflict: reads at unit q4^((r>>1)&3)
// spread 16 rows over 8 bank-sets -> 2-way = free (m136).
// Same 64B span per 4-thread group -> source coalescing unchanged.
__device__ __forceinline__ void stage_ht(const u16* __restrict__ gbase, int K,
                                         u16* __restrict__ dst, int t) {
#pragma unroll
  for (int j2 = 0; j2 < 2; j2++) {
    const int u = t + j2 * 512;
    const int r = u >> 2, cu = u & 3;       // 4 x 16B units per 64B row
    const int cs = cu ^ ((r >> 1) & 3);     // inverse-swizzled source unit
    gload16(gbase + (size_t)r * K + cs * 8, &dst[u * 8]);
  }
}

// ---------------------------------------------------------------------------
// GEMM, 256x256 tile, 8-phase deep pipeline (T3+T4 counted-vmcnt + T5 + T2):
// C[m][n] = sum_k A[m][k]*W[n][k] + bias[n].  512 thr / 8 waves (2M x 4N),
// BK=64 split into 2 k-halves; half-tile = [256][32] u16 per operand.
// LDS: ring of 4 slots per operand (2dbuf x 2kh) = 128 KB.
// Per group g (=2*kt+kh), two phases:
//   ph A: 12 swizzled ds_read_b128 | stage A-ht(g+3) |
//         BARRIER | setprio1 | 16 MFMA (j=0,1) | setprio0 | BARRIER
//   ph B: stage B-ht(g+3) | setprio1 | 16 MFMA (j=2,3) | setprio0 |
//         [tile end: s_waitcnt vmcnt(4); vmcnt(0) before last tile] | BARRIER
// All barriers sched_barrier-pinned raw s_barrier (no vmcnt drain);
// loads stay in flight across barriers (3 half-tile-groups ahead).
// MODE 0: scatter epilogue into bf16 Q/K/V; Q pre-scaled by 1/sqrt(d).
// MODE 1: fp32 C + bias.
// ---------------------------------------------------------------------------
template <int MODE>
__global__ __launch_bounds__(512) void gemm_8ph(const u16* __restrict__ Ab,
                                                const u16* __restrict__ Bw,
                                                const float* __restrict__ bias,
                                                float* __restrict__ outf,
                                                u16* __restrict__ oq,
                                                u16* __restrict__ ok,
                                                u16* __restrict__ ov,
                                                int K, int N) {
  __shared__ u16 As[4][256 * 32];   // 4 x 16 KB
  __shared__ u16 Bs[4][256 * 32];   // 4 x 16 KB
  const int t    = threadIdx.x;
  const int lane = t & 63;
  const int wv   = t >> 6;          // 0..7
  const int wr   = wv >> 2, wc = wv & 3;
  const int q4   = lane >> 4, l15 = lane & 15;

  // ---- XCD-aware block swizzle (bijective: nwg % 8 == 0) ----
  const int nwgx = gridDim.x;
  const int nwg  = nwgx * gridDim.y;
  int bid = blockIdx.y * nwgx + blockIdx.x;
  const int cpx = nwg >> 3;
  bid = (bid & 7) * cpx + (bid >> 3);
  const int m0 = (bid / nwgx) * 256, n0 = (bid % nwgx) * 256;

  const u16* Abase = Ab + (size_t)m0 * K;
  const u16* Bbase = Bw + (size_t)n0 * K;
  const int NT = K >> 6;            // K-tiles of 64
  const int NHT = 2 * NT;           // k-half groups

  f32x4 acc[8][4] = {};

  // ---- prologue: stage ht 0,1,2 (A,B interleaved); keep newest ht in flight
#pragma unroll
  for (int m = 0; m < 3; m++) {
    const int koff = (m >> 1) * 64 + (m & 1) * 32;
    stage_ht(Abase + koff, K, &As[m & 3][0], t);
    stage_ht(Bbase + koff, K, &Bs[m & 3][0], t);
  }
  asm volatile("s_waitcnt vmcnt(4)" ::: "memory");   // ht0,ht1 landed (this wave)
  barrier_pinned();                                  // -> landed for ALL waves

  for (int kt = 0; kt < NT; kt++) {
#pragma unroll
    for (int kh = 0; kh < 2; kh++) {
      const int g  = 2 * kt + kh;
      const int sl = g & 3;
      const u16* Asl = &As[sl][0];
      const u16* Bsl = &Bs[sl][0];

      // ---- phase A: swizzled ds-reads + A-stage + barrier + MFMA + barrier ----
      bf16x8 af[8], bfr[4];
#pragma unroll
      for (int i = 0; i < 8; i++) {
        const int ra = wr * 128 + i * 16 + l15;
        af[i] = *(const bf16x8*)&Asl[ra * 32 + (q4 ^ ((ra >> 1) & 3)) * 8];
      }
#pragma unroll
      for (int j = 0; j < 4; j++) {
        const int rb = wc * 64 + j * 16 + l15;
        bfr[j] = *(const bf16x8*)&Bsl[rb * 32 + (q4 ^ ((rb >> 1) & 3)) * 8];
      }

      const int ms = g + 3;                       // stage 3 half-tile-groups ahead
      const int koff = (ms >> 1) * 64 + (ms & 1) * 32;
      if (ms < NHT) stage_ht(Abase + koff, K, &As[ms & 3][0], t);

      barrier_pinned();
      __builtin_amdgcn_s_setprio(1);
#pragma unroll
      for (int i = 0; i < 8; i++) {
        acc[i][0] = __builtin_amdgcn_mfma_f32_16x16x32_bf16(af[i], bfr[0], acc[i][0], 0, 0, 0);
        acc[i][1] = __builtin_amdgcn_mfma_f32_16x16x32_bf16(af[i], bfr[1], acc[i][1], 0, 0, 0);
      }
      __builtin_amdgcn_s_setprio(0);
      barrier_pinned();

      // ---- phase B: B-stage + MFMA(j=2,3) + [boundary vmcnt] + barrier ----
      if (ms < NHT) stage_ht(Bbase + koff, K, &Bs[ms & 3][0], t);
      __builtin_amdgcn_s_setprio(1);
#pragma unroll
      for (int i = 0; i < 8; i++) {
        acc[i][2] = __builtin_amdgcn_mfma_f32_16x16x32_bf16(af[i], bfr[2], acc[i][2], 0, 0, 0);
        acc[i][3] = __builtin_amdgcn_mfma_f32_16x16x32_bf16(af[i], bfr[3], acc[i][3], 0, 0, 0);
      }
      __builtin_amdgcn_s_setprio(0);
      if (kh == 1) {
        if (kt < NT - 2)       asm volatile("s_waitcnt vmcnt(4)" ::: "memory");
        else if (kt == NT - 2) asm volatile("s_waitcnt vmcnt(0)" ::: "memory");
      }
      barrier_pinned();
    }
  }

  // ---- epilogue ----
#pragma unroll
  for (int j = 0; j < 4; j++) {
    const int gn = n0 + wc * 64 + j * 16 + l15;
    const float bv = bias[gn];
#pragma unroll
    for (int i = 0; i < 8; i++) {
      const int gmb = m0 + wr * 128 + i * 16 + q4 * 4;
#pragma unroll
      for (int rr = 0; rr < 4; rr++) {
        float val = acc[i][j][rr] + bv;
        const int gm = gmb + rr;
        if (MODE == 1) {
          outf[(size_t)gm * N + gn] = val;
        } else {
          const int b = gm >> 11, s = gm & (SEQ - 1);
          const int d = gn & (HDIM - 1);
          if (gn < 4096) {
            // fold attention scale 1/sqrt(128) into Q (commutes with RoPE)
            val *= 0.08838834764831845f;
            const int hh = gn >> 7;
            oq[((size_t)(b * NHEADS + hh) * SEQ + s) * HDIM + d] = f2b(val);
          } else if (gn < 5120) {
            const int hh = (gn - 4096) >> 7;
            ok[((size_t)(b * NKV + hh) * SEQ + s) * HDIM + d] = f2b(val);
          } else {
            const int hh = (gn - 5120) >> 7;
            ov[((size_t)(b * NKV + hh) * SEQ + s) * HDIM + d] = f2b(val);
          }
        }
      }
    }
  }
}

// ---------------------------------------------------------------------------
// RoPE in place on bf16 Q and K; cos/sin in fp32.
// ---------------------------------------------------------------------------
__global__ __launch_bounds__(256) void rope_kernel(u16* __restrict__ q, u16* __restrict__ kk,
                                                   int qrows, int totrows) {
  const int idx = blockIdx.x * 256 + threadIdx.x;
  const int row = idx >> 6;
  const int i   = idx & 63;
  if (row >= totrows) return;
  u16* base;
  int r;
  if (row < qrows) { base = q  + (size_t)row * HDIM;           r = row; }
  else             { base = kk + (size_t)(row - qrows) * HDIM; r = row - qrows; }
  const int s = r & (SEQ - 1);
  const float l2theta = 13.287712379549449f;  // log2(10000)
  const float inv = exp2f(-((float)(2 * i) * (1.0f / 128.0f)) * l2theta);
  const float ang = (float)s * inv;
  const float c  = cosf(ang);
  const float sn = sinf(ang);
  const u32 xv = *(const u32*)&base[2 * i];
  const float xr = b2f_lo(xv), xi = b2f_hi(xv);
  *(u32*)&base[2 * i] = pk(xr * c - xi * sn, xr * sn + xi * c);
}

// ---------------------------------------------------------------------------
// MFMA flash attention (causal, GQA group=4), SWAPPED-QK^T softmax.
// (unchanged from Round 6 -- launch_bounds(256,2), no scratch spill)
// ---------------------------------------------------------------------------
__global__ __launch_bounds__(256, 2) void attn_mfma(const u16* __restrict__ q,
                                                    const u16* __restrict__ k,
                                                    const u16* __restrict__ v,
                                                    u16* __restrict__ out) {
  __shared__ u16 Ks[64 * 136];       // [key][d], stride 136 u16 (272B)
  __shared__ u16 VtBuf[128 * 72];    // [d][key-swizzled], stride 72 u16 (144B)
  __shared__ u32 Ps32[4 * 32 * 36];  // per wave: [row][key-pair], stride 36 u32
  u32* Vt32 = (u32*)VtBuf;           // row stride 36 u32

  const int t    = threadIdx.x;
  const int lane = t & 63;
  const int w    = t >> 6;
  const int q4   = lane >> 4, l15 = lane & 15;
  const int qb   = 15 - (int)blockIdx.x;   // heavy blocks first
  const int h = blockIdx.y, b = blockIdx.z;
  const int m0 = qb * 128;
  const int mw = m0 + w * 32;              // wave's first q-row
  const int kvh = h >> 2;
  const u16* Qp = q + (size_t)(b * NHEADS + h) * SEQ * HDIM;
  const u16* Kp = k + (size_t)(b * NKV + kvh) * SEQ * HDIM;
  const u16* Vp = v + (size_t)(b * NKV + kvh) * SEQ * HDIM;

  // Q fragments (held in registers; Q already scaled by 1/sqrt(d))
  bf16x8 qf[2][4];
#pragma unroll
  for (int rt = 0; rt < 2; rt++)
#pragma unroll
    for (int kk = 0; kk < 4; kk++)
      qf[rt][kk] = *(const bf16x8*)&Qp[(size_t)(mw + rt * 16 + l15) * HDIM + kk * 32 + q4 * 8];

  f32x4 oacc[2][8] = {};
  float mrow[2], lrow[2];
  mrow[0] = mrow[1] = -1e30f;
  lrow[0] = lrow[1] = 0.f;

  u32* Pw32 = &Ps32[w * 32 * 36];

  const int nch = qb * 2 + 2;
  for (int kc = 0; kc < nch; kc++) {
    // ---- stage K: row-major, vector 16B units, coalesced (overlaps prev PV) ----
#pragma unroll
    for (int i = 0; i < 4; i++) {
      const int u = t + i * 256;           // 1024 units of 16B
      const int r = u >> 4, c = (u & 15) * 8;
      *(uint4*)&Ks[r * 136 + c] = *(const uint4*)&Kp[(size_t)(kc * 64 + r) * HDIM + c];
    }
    // ---- issue V loads now; consumed after softmax (latency hides under it) ----
    uint2 e0[4], e1[4];
#pragma unroll
    for (int i = 0; i < 4; i++) {
      const int tau = t + i * 256;         // 1024 tasks
      const int k2 = tau >> 5, dq = tau & 31;
      e0[i] = *(const uint2*)&Vp[(size_t)(kc * 64 + 2 * k2) * HDIM + dq * 4];
      e1[i] = *(const uint2*)&Vp[(size_t)(kc * 64 + 2 * k2 + 1) * HDIM + dq * 4];
    }
    __syncthreads();   // A: Ks published; prev-chunk Vt readers all done

    const bool part = (kc * 64 <= mw + 31);
    if (part) {
      const bool fullch = (kc * 64 + 63 <= mw);  // wave-uniform: no masking needed
      // ---- S^T = K Q^T (swapped operands) ----
      f32x4 sacc[2][4] = {};
      __builtin_amdgcn_s_setprio(1);
#pragma unroll
      for (int ct = 0; ct < 4; ct++) {
#pragma unroll
        for (int kk = 0; kk < 4; kk++) {
          const bf16x8 kb = *(const bf16x8*)&Ks[(ct * 16 + l15) * 136 + kk * 32 + q4 * 8];
          sacc[0][ct] = __builtin_amdgcn_mfma_f32_16x16x32_bf16(kb, qf[0][kk], sacc[0][ct], 0, 0, 0);
          sacc[1][ct] = __builtin_amdgcn_mfma_f32_16x16x32_bf16(kb, qf[1][kk], sacc[1][ct], 0, 0, 0);
        }
      }
      __builtin_amdgcn_s_setprio(0);
      // ---- softmax: lane owns 16 keys of q-row (rt*16+l15) ----
#pragma unroll
      for (int rt = 0; rt < 2; rt++) {
        float p[4][4];
        float cm[4];
        const int mm = mw + rt * 16 + l15;
#pragma unroll
        for (int ct = 0; ct < 4; ct++) {
#pragma unroll
          for (int rr = 0; rr < 4; rr++) {
            float s = sacc[rt][ct][rr];
            if (!fullch) {
              const int key = kc * 64 + ct * 16 + q4 * 4 + rr;
              s = (key <= mm) ? s : -1e30f;
            }
            p[ct][rr] = s;
          }
          cm[ct] = fmaxf(fmaxf(p[ct][0], p[ct][1]), fmaxf(p[ct][2], p[ct][3]));
        }
        float vmax = fmaxf(fmaxf(cm[0], cm[1]), fmaxf(cm[2], cm[3]));
        vmax = fmaxf(vmax, __shfl_xor(vmax, 16));
        vmax = fmaxf(vmax, __shfl_xor(vmax, 32));
        const float nm = fmaxf(mrow[rt], vmax);
        const float alpha = __expf(mrow[rt] - nm);
        mrow[rt] = nm;
        float cs[4];
#pragma unroll
        for (int ct = 0; ct < 4; ct++) {
#pragma unroll
          for (int rr = 0; rr < 4; rr++) p[ct][rr] = __expf(p[ct][rr] - nm);
          cs[ct] = (p[ct][0] + p[ct][1]) + (p[ct][2] + p[ct][3]);
        }
        lrow[rt] = lrow[rt] * alpha + ((cs[0] + cs[1]) + (cs[2] + cs[3]));
        // P -> LDS, packed u32 key-pairs (8B per ct); row spans u32 0..31
#pragma unroll
        for (int ct = 0; ct < 4; ct++) {
          uint2 w2;
          w2.x = pk(p[ct][0], p[ct][1]);
          w2.y = pk(p[ct][2], p[ct][3]);
          *(uint2*)&Pw32[(rt * 16 + l15) * 36 + ct * 8 + q4 * 2] = w2;
        }
        // alpha -> PV layout (row q4*4+rr) and rescale O
        float alT[4];
#pragma unroll
        for (int rr = 0; rr < 4; rr++) alT[rr] = __shfl(alpha, q4 * 4 + rr, 64);
#pragma unroll
        for (int dt = 0; dt < 8; dt++)
#pragma unroll
          for (int rr = 0; rr < 4; rr++) oacc[rt][dt][rr] *= alT[rr];
      }
    }
    // ---- commit V transposed: u32 key-pair packing + XOR group swizzle ----
#pragma unroll
    for (int i = 0; i < 4; i++) {
      const int tau = t + i * 256;
      const int k2 = tau >> 5, dq = tau & 31;
      u32 wj[4];
      wj[0] = (e0[i].x & 0xFFFFu) | (e1[i].x << 16);
      wj[1] = (e0[i].x >> 16)     | (e1[i].x & 0xFFFF0000u);
      wj[2] = (e0[i].y & 0xFFFFu) | (e1[i].y << 16);
      wj[3] = (e0[i].y >> 16)     | (e1[i].y & 0xFFFF0000u);
      const int g = k2 >> 2;
#pragma unroll
      for (int j = 0; j < 4; j++) {
        const int d = dq * 4 + j;
        const int gs = g ^ ((d >> 3) & 7);
        Vt32[d * 36 + gs * 4 + (k2 & 3)] = wj[j];
      }
    }
    __syncthreads();   // B: Vt published

    if (part) {
      // ---- O += P V ----
      __builtin_amdgcn_s_setprio(1);
#pragma unroll
      for (int kk2 = 0; kk2 < 2; kk2++) {
        bf16x8 pa[2];
        pa[0] = *(const bf16x8*)&Pw32[(l15) * 36 + kk2 * 16 + q4 * 4];
        pa[1] = *(const bf16x8*)&Pw32[(16 + l15) * 36 + kk2 * 16 + q4 * 4];
#pragma unroll
        for (int dt = 0; dt < 8; dt++) {
          const int d = dt * 16 + l15;
          const int gs = (kk2 * 4 + q4) ^ ((d >> 3) & 7);
          const bf16x8 vb = *(const bf16x8*)&Vt32[d * 36 + gs * 4];
          oacc[0][dt] = __builtin_amdgcn_mfma_f32_16x16x32_bf16(pa[0], vb, oacc[0][dt], 0, 0, 0);
          oacc[1][dt] = __builtin_amdgcn_mfma_f32_16x16x32_bf16(pa[1], vb, oacc[1][dt], 0, 0, 0);
        }
      }
      __builtin_amdgcn_s_setprio(0);
    }
  }

  // ---- epilogue: reduce l partials (4 q4-lanes), transpose to PV layout,
  //      O / l -> attn buffer [b][s][h*128+d] ----
#pragma unroll
  for (int rt = 0; rt < 2; rt++) {
    float ls = lrow[rt];
    ls += __shfl_xor(ls, 16);
    ls += __shfl_xor(ls, 32);
#pragma unroll
    for (int rr = 0; rr < 4; rr++) {
      const float lt = __shfl(ls, q4 * 4 + rr, 64);
      const float inv = 1.0f / lt;
      const int mm = mw + rt * 16 + q4 * 4 + rr;
      u16* op = &out[((size_t)(b * SEQ + mm)) * DMODEL + h * HDIM + l15];
#pragma unroll
      for (int dt = 0; dt < 8; dt++)
        op[dt * 16] = f2b(oacc[rt][dt][rr] * inv);
    }
  }
}

// ---------------------------------------------------------------------------
extern "C" void kernel_launch(void* const* d_in, const int* in_sizes, int n_in,
                              void* d_out, int out_size, void* d_ws, size_t ws_size,
                              hipStream_t stream) {
  const float* x     = (const float*)d_in[0];
  const float* w_qkv = (const float*)d_in[1];
  const float* b_qkv = (const float*)d_in[2];
  const float* w_o   = (const float*)d_in[3];
  const float* b_o   = (const float*)d_in[4];
  float* out = (float*)d_out;

  const size_t QN = (size_t)BATCH * NHEADS * SEQ * HDIM;   // 16.78M u16
  const size_t KN = (size_t)BATCH * NKV * SEQ * HDIM;      //  4.19M u16

  u16* q    = (u16*)d_ws;
  u16* k    = q + QN;
  u16* v    = k + KN;
  u16* attn = v + KN;
  u16* wb   = attn + QN;   // bf16 weight buffer: w_qkv (25.17M u16), reused for w_o
  u16* xb   = attn;        // bf16 x ALIASES attn: x is dead before attn_mfma writes

  const dim3 blk(256);
  const dim3 blk512(512);

  // ---- convert x and w_qkv -> bf16 ----
  const int n8_x = BATCH * SEQ * DMODEL / 8;
  f32_to_bf16<<<dim3(n8_x / 256), blk, 0, stream>>>(x, xb, n8_x);
  const int n8_qkv = QKV_DIM * DMODEL / 8;
  f32_to_bf16<<<dim3(n8_qkv / 256), blk, 0, stream>>>(w_qkv, wb, n8_qkv);

  // ---- QKV GEMM: 256^2 8-phase; grid 24 x 16 = 384 blocks (%8==0) ----
  gemm_8ph<0><<<dim3(QKV_DIM / 256, (BATCH * SEQ) / 256), blk512, 0, stream>>>(
      xb, wb, b_qkv, nullptr, q, k, v, DMODEL, QKV_DIM);

  const int qrows = BATCH * NHEADS * SEQ;
  const int totrows = qrows + BATCH * NKV * SEQ;
  rope_kernel<<<dim3((totrows * 64) / 256), blk, 0, stream>>>(q, k, qrows, totrows);

  attn_mfma<<<dim3(SEQ / 128, NHEADS, BATCH), blk, 0, stream>>>(q, k, v, attn);

  // ---- convert w_o -> bf16 (reuses wb; w_qkv copy is dead now) ----
  const int n8_o = DMODEL * DMODEL / 8;
  f32_to_bf16<<<dim3(n8_o / 256), blk, 0, stream>>>(w_o, wb, n8_o);

  // ---- output GEMM: grid 16 x 16 = 256 blocks (%8==0) ----
  gemm_8ph<1><<<dim3(DMODEL / 256, (BATCH * SEQ) / 256), blk512, 0, stream>>>(
      attn, wb, b_o, out, nullptr, nullptr, nullptr, DMODEL, DMODEL);
}